// Round 13
// baseline (348.739 us; speedup 1.0000x reference)
//
#include <hip/hip_runtime.h>

#define H 1024
#define UNITS 1024
#define BATCH 32
#define SEQ 2048
#define M_TOT (BATCH * SEQ)  // 65536

typedef __attribute__((ext_vector_type(8))) short bf16x8;
typedef __attribute__((ext_vector_type(8))) unsigned short u16x8;
typedef __attribute__((ext_vector_type(4))) float f32x4;

__device__ __forceinline__ unsigned short f2bf(float f) {
  union { float f; unsigned u; } x; x.f = f;
  unsigned r = x.u + 0x7FFFu + ((x.u >> 16) & 1u);  // RTN-even
  return (unsigned short)(r >> 16);
}
__device__ __forceinline__ float bf2f(unsigned short h) {
  union { unsigned u; float f; } x; x.u = (unsigned)h << 16;
  return x.f;
}

// async global->LDS, 16B per lane; LDS dest = wave-uniform base + lane*16
__device__ __forceinline__ void gll16(const unsigned short* g, unsigned short* l) {
  __builtin_amdgcn_global_load_lds(
      (const __attribute__((address_space(1))) void*)g,
      (__attribute__((address_space(3))) void*)l, 16, 0, 0);
}

// ---- values fp32 -> bf16 (one-shot, BW-bound) ----
__global__ void k_cast(const float* __restrict__ in, unsigned short* __restrict__ out) {
  size_t i = ((size_t)blockIdx.x * 256 + threadIdx.x) * 8;
  float4 v0 = *reinterpret_cast<const float4*>(in + i);
  float4 v1 = *reinterpret_cast<const float4*>(in + i + 4);
  union { unsigned short h[8]; u16x8 v; } p;
  p.h[0] = f2bf(v0.x); p.h[1] = f2bf(v0.y); p.h[2] = f2bf(v0.z); p.h[3] = f2bf(v0.w);
  p.h[4] = f2bf(v1.x); p.h[5] = f2bf(v1.y); p.h[6] = f2bf(v1.z); p.h[7] = f2bf(v1.w);
  *reinterpret_cast<u16x8*>(out + i) = p.v;
}

// ---- W1 [H][U] fp32 -> W1T [U][H] bf16 ----
__global__ void k_transpose_w1(const float* __restrict__ W1, unsigned short* __restrict__ W1T) {
  __shared__ float tile[32][33];
  int bx = blockIdx.x, by = blockIdx.y;
  int tx = threadIdx.x, ty = threadIdx.y;
#pragma unroll
  for (int i = 0; i < 4; ++i)
    tile[ty + i * 8][tx] = W1[(by * 32 + ty + i * 8) * UNITS + bx * 32 + tx];
  __syncthreads();
#pragma unroll
  for (int i = 0; i < 4; ++i)
    W1T[(bx * 32 + ty + i * 8) * H + by * 32 + tx] = f2bf(tile[tx][ty + i * 8]);
}

// ---- projq[b][u] = query[b,:] @ W2[:,u] + b2[u]  (fp32) ----
__global__ void k_projq(const float* __restrict__ query, const float* __restrict__ W2,
                        const float* __restrict__ b2, float* __restrict__ projq) {
  __shared__ float q[H];
  int b = blockIdx.x;
  int u = blockIdx.y * 256 + threadIdx.x;
  for (int i = threadIdx.x; i < H; i += 256) q[i] = query[b * H + i];
  __syncthreads();
  float acc = 0.f;
#pragma unroll 8
  for (int k = 0; k < H; ++k) acc = fmaf(q[k], W2[k * UNITS + u], acc);
  projq[b * UNITS + u] = acc + b2[u];
}

// ============ 256x256 4-phase/K-tile fused GEMM + tanh + dot(V) ==============
// The untested cell: R4's m201-faithful phase structure + R7's PROVEN
// conflict-free packed LDS layout + corrected wait placement.
//   LDS: As/Bs[2 buf][2 khalf][128][64]; K-half tile [256 m][32 k] packed
//   2 rows per 128-B LDS row (R7: 0 conflicts measured).
//   4 phases per K-tile (BK=64): (k0,nL),(k0,nH),(k1,nL),(k1,nH), 16 MFMA ea.
//   Stage for tile c+1, one half per phase: ph0->A_k0, ph1->B_k0,
//   ph2->A_k1, ph3->B_k1 (2 gll16/wave each).
//   Waits: {vmcnt(4); s_barrier} at ENTRY of ph0 and ph2 ONLY — vmcnt is
//   per-wave, so the counted wait must precede a barrier that precedes the
//   ds_reads; then all waves' gll16 contributions to the halves read in the
//   next two phases are landed. Ledger: 8 outstanding at each check, oldest
//   4 = exactly {A,B}_khalf(c) about to be read; >=4-phase cushion per load.
//   lgkm(0)+sched_barrier (rule 18) before each setprio'd 16-MFMA cluster.
//   Buffer reuse race-free: stage into As[nbuf][kh] issues >=2 barriers after
//   the last readers of that region drained their lgkm.
#define BM 256
#define BN 256
#define NKT 16  // K-tiles of 64

__global__ __launch_bounds__(512, 2) void k_score3(
    const unsigned short* __restrict__ Vb,   // values bf16 [M_TOT][H]
    const unsigned short* __restrict__ W1T,  // [UNITS][H] bf16
    const float* __restrict__ b1,
    const float* __restrict__ projq,         // [BATCH][UNITS]
    const float* __restrict__ V,
    float* __restrict__ scores)              // [M_TOT], pre-zeroed
{
  __shared__ unsigned short As[2][2][128][64];  // 64 KB
  __shared__ unsigned short Bs[2][2][128][64];  // 64 KB

  const int tid = threadIdx.x;
  const int lane = tid & 63;
  const int wave = tid >> 6;        // 0..7
  const int wm = wave >> 2;         // 0..1 -> rows wm*128..+128
  const int wn = wave & 3;          // 0..3 -> cols wn*64..+64
  const int li = lane & 15, hi = lane >> 4;
  const int lr2 = li >> 1;
  const int pcol = (((((li & 1) << 2) + hi) ^ lr2) & 7) << 3;  // read slot (halves)

  // XCD-bijective swizzle: all 4 N-tiles of an M-tile on one XCD, consecutive.
  const int g = blockIdx.x;
  const int xcd = g & 7;
  const int local = g >> 3;          // 0..127
  const int n_t = local & 3;
  const int m_t = xcd + ((local >> 2) << 3);  // 0..255, bijective
  const int m0 = m_t * BM;
  const int n0 = n_t * BN;

  // staging (R7-proven): chunk = 16 logical rows x 32 halves = 1 KB = 1 gll16
  // lane l: s=(l&7)^(l>>3); srow=2*(l>>3)+(s>>2); scol=(s&3)*8
  const int sL = (lane & 7) ^ (lane >> 3);
  const int srow = 2 * (lane >> 3) + (sL >> 2);
  const int scol = (sL & 3) << 3;

  auto STAGE_A = [&](int bf, int kt, int kh) {
#pragma unroll
    for (int q = 0; q < 2; ++q) {
      int mb = wave * 32 + q * 16;
      gll16(&Vb[(size_t)(m0 + mb + srow) * H + kt * 64 + kh * 32 + scol],
            &As[bf][kh][wave * 16 + q * 8][0]);
    }
  };
  auto STAGE_B = [&](int bf, int kt, int kh) {
#pragma unroll
    for (int q = 0; q < 2; ++q) {
      int mb = wave * 32 + q * 16;
      gll16(&W1T[(size_t)(n0 + mb + srow) * H + kt * 64 + kh * 32 + scol],
            &Bs[bf][kh][wave * 16 + q * 8][0]);
    }
  };

  f32x4 acc[8][4] = {};
  bf16x8 a[8], bL0, bL1, bH0, bH1;

  // prologue: stage all 4 halves of K-tile 0 (8 loads, ledger order)
  STAGE_A(0, 0, 0);
  STAGE_B(0, 0, 0);
  STAGE_A(0, 0, 1);
  STAGE_B(0, 0, 1);

#pragma unroll 2
  for (int c = 0; c < NKT; ++c) {
    const int buf = c & 1, nbuf = buf ^ 1;
    const int cn = (c + 1 < NKT) ? c + 1 : NKT - 1;  // tail: dup-stage tile 15

    // ================ phase 0: k0, nL ================
    // oldest 4 outstanding = {A_k0(c), B_k0(c)}; all waves' landed after bar
    asm volatile("s_waitcnt vmcnt(4)" ::: "memory");
    __builtin_amdgcn_s_barrier();
#pragma unroll
    for (int i = 0; i < 8; ++i)
      a[i] = *reinterpret_cast<const bf16x8*>(&As[buf][0][wm * 64 + i * 8 + lr2][pcol]);
    bL0 = *reinterpret_cast<const bf16x8*>(&Bs[buf][0][wn * 32 + 0 * 8 + lr2][pcol]);
    bL1 = *reinterpret_cast<const bf16x8*>(&Bs[buf][0][wn * 32 + 1 * 8 + lr2][pcol]);
    STAGE_A(nbuf, cn, 0);
    asm volatile("s_waitcnt lgkmcnt(0)" ::: "memory");
    __builtin_amdgcn_sched_barrier(0);
    __builtin_amdgcn_s_setprio(1);
#pragma unroll
    for (int i = 0; i < 8; ++i) {
      acc[i][0] = __builtin_amdgcn_mfma_f32_16x16x32_bf16(a[i], bL0, acc[i][0], 0, 0, 0);
      acc[i][1] = __builtin_amdgcn_mfma_f32_16x16x32_bf16(a[i], bL1, acc[i][1], 0, 0, 0);
    }
    __builtin_amdgcn_s_setprio(0);
    __builtin_amdgcn_s_barrier();

    // ================ phase 1: k0, nH ================
    bH0 = *reinterpret_cast<const bf16x8*>(&Bs[buf][0][wn * 32 + 2 * 8 + lr2][pcol]);
    bH1 = *reinterpret_cast<const bf16x8*>(&Bs[buf][0][wn * 32 + 3 * 8 + lr2][pcol]);
    STAGE_B(nbuf, cn, 0);
    asm volatile("s_waitcnt lgkmcnt(0)" ::: "memory");
    __builtin_amdgcn_sched_barrier(0);
    __builtin_amdgcn_s_setprio(1);
#pragma unroll
    for (int i = 0; i < 8; ++i) {
      acc[i][2] = __builtin_amdgcn_mfma_f32_16x16x32_bf16(a[i], bH0, acc[i][2], 0, 0, 0);
      acc[i][3] = __builtin_amdgcn_mfma_f32_16x16x32_bf16(a[i], bH1, acc[i][3], 0, 0, 0);
    }
    __builtin_amdgcn_s_setprio(0);
    __builtin_amdgcn_s_barrier();

    // ================ phase 2: k1, nL ================
    // oldest 4 outstanding = {A_k1(c), B_k1(c)}
    asm volatile("s_waitcnt vmcnt(4)" ::: "memory");
    __builtin_amdgcn_s_barrier();
#pragma unroll
    for (int i = 0; i < 8; ++i)
      a[i] = *reinterpret_cast<const bf16x8*>(&As[buf][1][wm * 64 + i * 8 + lr2][pcol]);
    bL0 = *reinterpret_cast<const bf16x8*>(&Bs[buf][1][wn * 32 + 0 * 8 + lr2][pcol]);
    bL1 = *reinterpret_cast<const bf16x8*>(&Bs[buf][1][wn * 32 + 1 * 8 + lr2][pcol]);
    STAGE_A(nbuf, cn, 1);
    asm volatile("s_waitcnt lgkmcnt(0)" ::: "memory");
    __builtin_amdgcn_sched_barrier(0);
    __builtin_amdgcn_s_setprio(1);
#pragma unroll
    for (int i = 0; i < 8; ++i) {
      acc[i][0] = __builtin_amdgcn_mfma_f32_16x16x32_bf16(a[i], bL0, acc[i][0], 0, 0, 0);
      acc[i][1] = __builtin_amdgcn_mfma_f32_16x16x32_bf16(a[i], bL1, acc[i][1], 0, 0, 0);
    }
    __builtin_amdgcn_s_setprio(0);
    __builtin_amdgcn_s_barrier();

    // ================ phase 3: k1, nH ================
    bH0 = *reinterpret_cast<const bf16x8*>(&Bs[buf][1][wn * 32 + 2 * 8 + lr2][pcol]);
    bH1 = *reinterpret_cast<const bf16x8*>(&Bs[buf][1][wn * 32 + 3 * 8 + lr2][pcol]);
    STAGE_B(nbuf, cn, 1);
    asm volatile("s_waitcnt lgkmcnt(0)" ::: "memory");
    __builtin_amdgcn_sched_barrier(0);
    __builtin_amdgcn_s_setprio(1);
#pragma unroll
    for (int i = 0; i < 8; ++i) {
      acc[i][2] = __builtin_amdgcn_mfma_f32_16x16x32_bf16(a[i], bH0, acc[i][2], 0, 0, 0);
      acc[i][3] = __builtin_amdgcn_mfma_f32_16x16x32_bf16(a[i], bH1, acc[i][3], 0, 0, 0);
    }
    __builtin_amdgcn_s_setprio(0);
    __builtin_amdgcn_s_barrier();
  }

  // drain dangling dup-stage loads (never read; keep LDS writes quiesced)
  asm volatile("s_waitcnt vmcnt(0)" ::: "memory");
  __builtin_amdgcn_s_barrier();

  // epilogue: partial score[row] = sum_u tanh(acc + b1[u] + projq[b][u]) * V[u]
  const int b = m0 >> 11;  // BM=256 divides SEQ=2048 -> batch uniform per block
  float bias[4], vv[4];
#pragma unroll
  for (int j = 0; j < 4; ++j) {
    int u = n0 + wn * 64 + j * 16 + li;
    bias[j] = b1[u] + projq[b * UNITS + u];
    vv[j] = V[u];
  }
#pragma unroll
  for (int mi = 0; mi < 8; ++mi) {
#pragma unroll
    for (int r = 0; r < 4; ++r) {
      float s = 0.f;
#pragma unroll
      for (int j = 0; j < 4; ++j) {
        float x = acc[mi][j][r] + bias[j];
        float e = __expf(2.f * x);       // tanh(x) = 1 - 2/(e^(2x)+1)
        s += (1.f - 2.f / (e + 1.f)) * vv[j];
      }
      s += __shfl_xor(s, 1);
      s += __shfl_xor(s, 2);
      s += __shfl_xor(s, 4);
      s += __shfl_xor(s, 8);
      if (li == 0) {
        int row = m0 + wm * 128 + mi * 16 + hi * 4 + r;
        atomicAdd(&scores[row], s);
      }
    }
  }
}

// ---- fallback fp32-A score kernel (used only if ws too small) ----
#define FBM 128
#define FBN 128
#define FBK 64
#define LDK 72
__global__ __launch_bounds__(256) void k_score_f32(
    const float* __restrict__ values, const unsigned short* __restrict__ W1T,
    const float* __restrict__ b1, const float* __restrict__ projq,
    const float* __restrict__ V, float* __restrict__ scores)
{
  __shared__ unsigned short Asf[FBM][LDK];
  __shared__ unsigned short Bsf[FBN][LDK];
  const int tid = threadIdx.x;
  const int lane = tid & 63;
  const int wave = tid >> 6;
  const int wm = wave >> 1, wn = wave & 1;
  const int li = lane & 15, hi = lane >> 4;
  const int n0 = blockIdx.x * FBN;
  const int m0 = blockIdx.y * FBM;
  f32x4 acc[4][4] = {};
  for (int k0 = 0; k0 < H; k0 += FBK) {
    __syncthreads();
#pragma unroll
    for (int q = 0; q < 8; ++q) {
      int idx = q * 256 + tid;
      int row = idx >> 4;
      int kc = (idx & 15) << 2;
      float4 v = *reinterpret_cast<const float4*>(&values[(size_t)(m0 + row) * H + k0 + kc]);
      union { unsigned short h[4]; unsigned long long u64; } p;
      p.h[0] = f2bf(v.x); p.h[1] = f2bf(v.y); p.h[2] = f2bf(v.z); p.h[3] = f2bf(v.w);
      *reinterpret_cast<unsigned long long*>(&Asf[row][kc]) = p.u64;
    }
#pragma unroll
    for (int q = 0; q < 4; ++q) {
      int idx = q * 256 + tid;
      int row = idx >> 3;
      int kc = (idx & 7) << 3;
      *reinterpret_cast<u16x8*>(&Bsf[row][kc]) =
          *reinterpret_cast<const u16x8*>(&W1T[(size_t)(n0 + row) * H + k0 + kc]);
    }
    __syncthreads();
#pragma unroll
    for (int ks = 0; ks < 2; ++ks) {
      const int kofs = ks * 32 + 8 * hi;
      bf16x8 a[4], bb[4];
#pragma unroll
      for (int i = 0; i < 4; ++i)
        a[i] = *reinterpret_cast<const bf16x8*>(&Asf[wm * 64 + i * 16 + li][kofs]);
#pragma unroll
      for (int i = 0; i < 4; ++i)
        bb[i] = *reinterpret_cast<const bf16x8*>(&Bsf[wn * 64 + i * 16 + li][kofs]);
#pragma unroll
      for (int mi = 0; mi < 4; ++mi)
#pragma unroll
        for (int ni = 0; ni < 4; ++ni)
          acc[mi][ni] = __builtin_amdgcn_mfma_f32_16x16x32_bf16(a[mi], bb[ni], acc[mi][ni], 0, 0, 0);
    }
  }
  const int b = m0 >> 11;
  float bias[4], vv[4];
#pragma unroll
  for (int ni = 0; ni < 4; ++ni) {
    int u = n0 + wn * 64 + ni * 16 + li;
    bias[ni] = b1[u] + projq[b * UNITS + u];
    vv[ni] = V[u];
  }
#pragma unroll
  for (int mi = 0; mi < 4; ++mi) {
#pragma unroll
    for (int r = 0; r < 4; ++r) {
      float s = 0.f;
#pragma unroll
      for (int ni = 0; ni < 4; ++ni) {
        float x = acc[mi][ni][r] + bias[ni];
        float e = __expf(2.f * x);
        s += (1.f - 2.f / (e + 1.f)) * vv[ni];
      }
      s += __shfl_xor(s, 1);
      s += __shfl_xor(s, 2);
      s += __shfl_xor(s, 4);
      s += __shfl_xor(s, 8);
      if (li == 0) atomicAdd(&scores[m0 + wm * 64 + mi * 16 + hi * 4 + r], s);
    }
  }
}

// ---- softmax over S per batch; bv cancels ----
__global__ void k_softmax(const float* __restrict__ scores, float* __restrict__ wts) {
  __shared__ float red[8];
  int b = blockIdx.x;
  int t = threadIdx.x;
  float v[8];
  float mx = -3.4e38f;
#pragma unroll
  for (int i = 0; i < 8; ++i) {
    v[i] = scores[b * SEQ + i * 256 + t];
    mx = fmaxf(mx, v[i]);
  }
#pragma unroll
  for (int o = 1; o < 64; o <<= 1) mx = fmaxf(mx, __shfl_xor(mx, o));
  if ((t & 63) == 0) red[t >> 6] = mx;
  __syncthreads();
  mx = fmaxf(fmaxf(red[0], red[1]), fmaxf(red[2], red[3]));
  float sum = 0.f;
#pragma unroll
  for (int i = 0; i < 8; ++i) { v[i] = __expf(v[i] - mx); sum += v[i]; }
#pragma unroll
  for (int o = 1; o < 64; o <<= 1) sum += __shfl_xor(sum, o);
  if ((t & 63) == 0) red[4 + (t >> 6)] = sum;
  __syncthreads();
  float inv = 1.f / (red[4] + red[5] + red[6] + red[7]);
#pragma unroll
  for (int i = 0; i < 8; ++i) wts[b * SEQ + i * 256 + t] = v[i] * inv;
}

// ---- context from bf16 values: ctx[b][h] = sum_s w[b][s]*v[b][s][h] ----
__global__ void k_context_bf(const unsigned short* __restrict__ Vb,
                             const float* __restrict__ wts, float* __restrict__ ctx) {
  int b = blockIdx.x, sc = blockIdx.y;
  int h4 = threadIdx.x * 4;
  const unsigned short* vb = Vb + (size_t)b * SEQ * H;
  float a0 = 0, a1 = 0, a2 = 0, a3 = 0;
  int s0 = sc * 128;
#pragma unroll 4
  for (int s = s0; s < s0 + 128; ++s) {
    float w = wts[b * SEQ + s];
    ushort4 v = *reinterpret_cast<const ushort4*>(&vb[(size_t)s * H + h4]);
    a0 = fmaf(w, bf2f(v.x), a0);
    a1 = fmaf(w, bf2f(v.y), a1);
    a2 = fmaf(w, bf2f(v.z), a2);
    a3 = fmaf(w, bf2f(v.w), a3);
  }
  atomicAdd(&ctx[b * H + h4 + 0], a0);
  atomicAdd(&ctx[b * H + h4 + 1], a1);
  atomicAdd(&ctx[b * H + h4 + 2], a2);
  atomicAdd(&ctx[b * H + h4 + 3], a3);
}

// ---- fp32 context (fallback path) ----
__global__ void k_context(const float* __restrict__ values, const float* __restrict__ wts,
                          float* __restrict__ ctx) {
  int b = blockIdx.x, hc = blockIdx.y, sc = blockIdx.z;
  int h = hc * 256 + threadIdx.x;
  const float* vb = values + (size_t)b * SEQ * H;
  float acc = 0.f;
  int s0 = sc * 128;
#pragma unroll 4
  for (int s = s0; s < s0 + 128; ++s)
    acc = fmaf(wts[b * SEQ + s], vb[(size_t)s * H + h], acc);
  atomicAdd(&ctx[b * H + h], acc);
}

extern "C" void kernel_launch(void* const* d_in, const int* in_sizes, int n_in,
                              void* d_out, int out_size, void* d_ws, size_t ws_size,
                              hipStream_t stream) {
  (void)in_sizes; (void)n_in; (void)out_size;
  const float* query  = (const float*)d_in[0];
  const float* values = (const float*)d_in[1];
  const float* W1     = (const float*)d_in[2];
  const float* b1     = (const float*)d_in[3];
  const float* W2     = (const float*)d_in[4];
  const float* b2     = (const float*)d_in[5];
  const float* V      = (const float*)d_in[6];
  // d_in[7] = bv: cancels in softmax -> unused.

  float* out = (float*)d_out;
  float* ctx = out;             // [32][1024]
  float* wts = out + BATCH * H; // [32][2048]

  const size_t vb_bytes = (size_t)M_TOT * H * 2;  // 128 MB
  const size_t need = vb_bytes + (2u << 20) + (256u << 10) + (128u << 10);

  if (ws_size >= need) {
    char* ws = (char*)d_ws;
    unsigned short* Vb  = (unsigned short*)ws;
    unsigned short* W1T = (unsigned short*)(ws + vb_bytes);
    float* scores = (float*)(ws + vb_bytes + (2u << 20));
    float* projq  = (float*)(ws + vb_bytes + (2u << 20) + (256u << 10));

    hipMemsetAsync(scores, 0, M_TOT * sizeof(float), stream);
    hipMemsetAsync(ctx, 0, BATCH * H * sizeof(float), stream);

    k_cast<<<(M_TOT * H / 8) / 256, 256, 0, stream>>>(values, Vb);
    k_transpose_w1<<<dim3(32, 32), dim3(32, 8), 0, stream>>>(W1, W1T);
    k_projq<<<dim3(32, 4), 256, 0, stream>>>(query, W2, b2, projq);
    k_score3<<<(M_TOT / BM) * (UNITS / BN), 512, 0, stream>>>(Vb, W1T, b1, projq, V, scores);
    k_softmax<<<BATCH, 256, 0, stream>>>(scores, wts);
    k_context_bf<<<dim3(BATCH, 16), 256, 0, stream>>>(Vb, wts, ctx);
  } else {
    char* ws = (char*)d_ws;
    unsigned short* W1T = (unsigned short*)ws;
    float* scores = (float*)(ws + (2u << 20));
    float* projq  = (float*)(ws + (2u << 20) + (256u << 10));

    hipMemsetAsync(scores, 0, M_TOT * sizeof(float), stream);
    hipMemsetAsync(ctx, 0, BATCH * H * sizeof(float), stream);

    k_transpose_w1<<<dim3(32, 32), dim3(32, 8), 0, stream>>>(W1, W1T);
    k_projq<<<dim3(32, 4), 256, 0, stream>>>(query, W2, b2, projq);
    k_score_f32<<<dim3(UNITS / FBN, M_TOT / FBM), 256, 0, stream>>>(values, W1T, b1, projq, V, scores);
    k_softmax<<<BATCH, 256, 0, stream>>>(scores, wts);
    k_context<<<dim3(BATCH, H / 256, 16), 256, 0, stream>>>(values, wts, ctx);
  }
}

// Round 14
// 329.667 us; speedup vs baseline: 1.0579x; 1.0579x over previous
//
#include <hip/hip_runtime.h>

#define H 1024
#define UNITS 1024
#define BATCH 32
#define SEQ 2048
#define M_TOT (BATCH * SEQ)  // 65536

typedef __attribute__((ext_vector_type(8))) short bf16x8;
typedef __attribute__((ext_vector_type(8))) unsigned short u16x8;
typedef __attribute__((ext_vector_type(4))) float f32x4;

__device__ __forceinline__ unsigned short f2bf(float f) {
  union { float f; unsigned u; } x; x.f = f;
  unsigned r = x.u + 0x7FFFu + ((x.u >> 16) & 1u);  // RTN-even
  return (unsigned short)(r >> 16);
}
__device__ __forceinline__ float bf2f(unsigned short h) {
  union { unsigned u; float f; } x; x.u = (unsigned)h << 16;
  return x.f;
}

// async global->LDS, 16B per lane; LDS dest = wave-uniform base + lane*16
__device__ __forceinline__ void gll16(const unsigned short* g, unsigned short* l) {
  __builtin_amdgcn_global_load_lds(
      (const __attribute__((address_space(1))) void*)g,
      (__attribute__((address_space(3))) void*)l, 16, 0, 0);
}

// ---- fused prep: values cast (blocks 0..2047) + W1 transpose (2048..3071)
//      + projq (3072..3199). One launch instead of three (gap trim).
__global__ void k_prep(const float* __restrict__ values, unsigned short* __restrict__ Vb,
                       const float* __restrict__ W1, unsigned short* __restrict__ W1T,
                       const float* __restrict__ query, const float* __restrict__ W2,
                       const float* __restrict__ b2, float* __restrict__ projq) {
  __shared__ float sh[1056];  // aliased: tile[32][33] (4224B) / q[1024] (4096B)
  const int blk = blockIdx.x;
  const int tid = threadIdx.x;
  if (blk < 2048) {
    // cast: grid-stride over 32768 units of 256 thr x 8 elems
    for (int u = blk; u < 32768; u += 2048) {
      size_t i = ((size_t)u * 256 + tid) * 8;
      float4 v0 = *reinterpret_cast<const float4*>(values + i);
      float4 v1 = *reinterpret_cast<const float4*>(values + i + 4);
      union { unsigned short h[8]; u16x8 v; } p;
      p.h[0] = f2bf(v0.x); p.h[1] = f2bf(v0.y); p.h[2] = f2bf(v0.z); p.h[3] = f2bf(v0.w);
      p.h[4] = f2bf(v1.x); p.h[5] = f2bf(v1.y); p.h[6] = f2bf(v1.z); p.h[7] = f2bf(v1.w);
      *reinterpret_cast<u16x8*>(Vb + i) = p.v;
    }
  } else if (blk < 3072) {
    float (*tile)[33] = reinterpret_cast<float(*)[33]>(sh);
    const int t = blk - 2048;
    const int bx = t & 31, by = t >> 5;
    const int tx = tid & 31, ty = tid >> 5;  // 32 x 8
#pragma unroll
    for (int i = 0; i < 4; ++i)
      tile[ty + i * 8][tx] = W1[(by * 32 + ty + i * 8) * UNITS + bx * 32 + tx];
    __syncthreads();
#pragma unroll
    for (int i = 0; i < 4; ++i)
      W1T[(bx * 32 + ty + i * 8) * H + by * 32 + tx] = f2bf(tile[tx][ty + i * 8]);
  } else {
    float* q = sh;
    const int t = blk - 3072;       // 0..127
    const int b = t >> 2;
    const int u = (t & 3) * 256 + tid;
    for (int i = tid; i < H; i += 256) q[i] = query[b * H + i];
    __syncthreads();
    float acc = 0.f;
#pragma unroll 8
    for (int k = 0; k < H; ++k) acc = fmaf(q[k], W2[k * UNITS + u], acc);
    projq[b * UNITS + u] = acc + b2[u];
  }
}

// ============ 256x256 fused GEMM + tanh + dot(V) -> scores ===================
// R8 skeleton (best, 183 us = 751 TF): ring-4 BK=32, depth-3 prefetch,
// counted vmcnt(8), R7-proven conflict-free packed layout (0 conflicts).
// NEW: cross-tile REGISTER pipeline — tile c's 12 ds_reads are issued, then
// lgkmcnt(12) waits only tile c-1's reads (the 12 new stay in flight), then
// the 32-MFMA cluster for tile c-1 runs: ds_read latency hides under MFMA
// within each wave (the serialization R8 still paid). Double fragment set
// aP/bP <-> aQ/bQ alternated by compile-time naming (rule 20).
// Barrier2 after the lgkm drain makes ring-4 reuse race-free: STAGE(c+3)
// writes buf (c+3)&3 == (c-1)&3; all waves' reads of that buf (tile c-1)
// drained at their lgkmcnt(12) BEFORE barrier2, and STAGE is after it.
// sched_barrier(0) pins MFMA after the wait (rule 18) and STAGE before MFMA.
#define BM 256
#define BN 256
#define NKT 32  // K-tiles of 32

__global__ __launch_bounds__(512, 2) void k_score3(
    const unsigned short* __restrict__ Vb,   // values bf16 [M_TOT][H]
    const unsigned short* __restrict__ W1T,  // [UNITS][H] bf16
    const float* __restrict__ b1,
    const float* __restrict__ projq,         // [BATCH][UNITS]
    const float* __restrict__ V,
    float* __restrict__ scores)              // [M_TOT], pre-zeroed
{
  __shared__ unsigned short As[4][128][64];  // 64 KB (ring of 4 K-tiles)
  __shared__ unsigned short Bs[4][128][64];  // 64 KB

  const int tid = threadIdx.x;
  const int lane = tid & 63;
  const int wave = tid >> 6;        // 0..7
  const int wm = wave >> 2;         // 0..1 -> rows wm*128..+128
  const int wn = wave & 3;          // 0..3 -> cols wn*64..+64
  const int li = lane & 15, hi = lane >> 4;
  const int lr2 = li >> 1;
  const int pcol = (((((li & 1) << 2) + hi) ^ lr2) & 7) << 3;  // read slot (halves)

  // XCD-bijective swizzle: all 4 N-tiles of an M-tile on one XCD, consecutive.
  const int g = blockIdx.x;
  const int xcd = g & 7;
  const int local = g >> 3;          // 0..127
  const int n_t = local & 3;
  const int m_t = xcd + ((local >> 2) << 3);  // 0..255, bijective
  const int m0 = m_t * BM;
  const int n0 = n_t * BN;

  // staging (R7-proven): chunk = 16 logical rows x 32 halves = 1 KB = 1 gll16
  // lane l: s=(l&7)^(l>>3); srow=2*(l>>3)+(s>>2); scol=(s&3)*8
  const int sL = (lane & 7) ^ (lane >> 3);
  const int srow = 2 * (lane >> 3) + (sL >> 2);
  const int scol = (sL & 3) << 3;

  auto STAGE_A = [&](int bf, int kt) {
#pragma unroll
    for (int q = 0; q < 2; ++q) {
      int mb = wave * 32 + q * 16;
      gll16(&Vb[(size_t)(m0 + mb + srow) * H + kt * 32 + scol],
            &As[bf][wave * 16 + q * 8][0]);
    }
  };
  auto STAGE_B = [&](int bf, int kt) {
#pragma unroll
    for (int q = 0; q < 2; ++q) {
      int mb = wave * 32 + q * 16;
      gll16(&W1T[(size_t)(n0 + mb + srow) * H + kt * 32 + scol],
            &Bs[bf][wave * 16 + q * 8][0]);
    }
  };

  f32x4 acc[8][4] = {};
  bf16x8 aP[8], bP[4], aQ[8], bQ[4];

  auto READS = [&](int c, bf16x8* rdA, bf16x8* rdB) {
    const int buf = c & 3;
#pragma unroll
    for (int i = 0; i < 8; ++i)
      rdA[i] = *reinterpret_cast<const bf16x8*>(&As[buf][wm * 64 + i * 8 + lr2][pcol]);
#pragma unroll
    for (int j = 0; j < 4; ++j)
      rdB[j] = *reinterpret_cast<const bf16x8*>(&Bs[buf][wn * 32 + j * 8 + lr2][pcol]);
  };
  auto MFMAS = [&](const bf16x8* mA, const bf16x8* mB) {
    __builtin_amdgcn_s_setprio(1);
#pragma unroll
    for (int i = 0; i < 8; ++i)
#pragma unroll
      for (int j = 0; j < 4; ++j)
        acc[i][j] = __builtin_amdgcn_mfma_f32_16x16x32_bf16(mA[i], mB[j], acc[i][j], 0, 0, 0);
    __builtin_amdgcn_s_setprio(0);
  };
  // iter c: reads(c)->rd*, lgkm(12) waits reads(c-1), bar2, STAGE(c+3),
  //         MFMA(c-1) from mm*
  auto BODY = [&](int c, bf16x8* rdA, bf16x8* rdB, const bf16x8* mmA, const bf16x8* mmB) {
    asm volatile("s_waitcnt vmcnt(8)" ::: "memory");  // tile c's own 4 landed
    __builtin_amdgcn_s_barrier();                     // all waves' tile-c landed
    READS(c, rdA, rdB);
    asm volatile("s_waitcnt lgkmcnt(12)" ::: "memory");  // tile c-1 reads done
    __builtin_amdgcn_sched_barrier(0);
    __builtin_amdgcn_s_barrier();   // ALL waves drained reads(c-1) -> buf reuse safe
    const int cn = (c + 3 < NKT) ? c + 3 : NKT - 1;   // tail: dup-stage
    STAGE_A((c + 3) & 3, cn);
    STAGE_B((c + 3) & 3, cn);
    __builtin_amdgcn_sched_barrier(0);  // keep STAGE issued before MFMA
    MFMAS(mmA, mmB);
  };

  // prologue: stage tiles 0,1,2 (12 loads/wave; issue order = ledger order)
  STAGE_A(0, 0); STAGE_B(0, 0);
  STAGE_A(1, 1); STAGE_B(1, 1);
  STAGE_A(2, 2); STAGE_B(2, 2);

  // iter 0 (no MFMA yet): reads(0) -> Q
  asm volatile("s_waitcnt vmcnt(8)" ::: "memory");
  __builtin_amdgcn_s_barrier();
  READS(0, aQ, bQ);
  asm volatile("s_waitcnt lgkmcnt(12)" ::: "memory");  // no-op (12 outstanding)
  __builtin_amdgcn_sched_barrier(0);
  __builtin_amdgcn_s_barrier();
  STAGE_A(3, 3);
  STAGE_B(3, 3);
  __builtin_amdgcn_sched_barrier(0);

  for (int c = 1; c <= NKT - 3; c += 2) {
    BODY(c, aP, bP, aQ, bQ);      // odd:  read P, MFMA tile c-1 (from Q)
    BODY(c + 1, aQ, bQ, aP, bP);  // even: read Q, MFMA tile c   (from P)
  }
  BODY(NKT - 1, aP, bP, aQ, bQ);  // c=31: read P, MFMA tile 30 (from Q)

  // final MFMA for tile 31 (regs in P)
  asm volatile("s_waitcnt lgkmcnt(0)" ::: "memory");
  __builtin_amdgcn_sched_barrier(0);
  MFMAS(aP, bP);
  asm volatile("s_waitcnt vmcnt(0)" ::: "memory");  // drain dangling dup-stages
  __builtin_amdgcn_s_barrier();

  // epilogue: partial score[row] = sum_u tanh(acc + b1[u] + projq[b][u]) * V[u]
  const int b = m0 >> 11;  // BM=256 divides SEQ=2048 -> batch uniform per block
  float bias[4], vv[4];
#pragma unroll
  for (int j = 0; j < 4; ++j) {
    int u = n0 + wn * 64 + j * 16 + li;
    bias[j] = b1[u] + projq[b * UNITS + u];
    vv[j] = V[u];
  }
#pragma unroll
  for (int mi = 0; mi < 8; ++mi) {
#pragma unroll
    for (int r = 0; r < 4; ++r) {
      float s = 0.f;
#pragma unroll
      for (int j = 0; j < 4; ++j) {
        float x = acc[mi][j][r] + bias[j];
        float e = __expf(2.f * x);       // tanh(x) = 1 - 2/(e^(2x)+1)
        s += (1.f - 2.f / (e + 1.f)) * vv[j];
      }
      s += __shfl_xor(s, 1);
      s += __shfl_xor(s, 2);
      s += __shfl_xor(s, 4);
      s += __shfl_xor(s, 8);
      if (li == 0) {
        int row = m0 + wm * 128 + mi * 16 + hi * 4 + r;
        atomicAdd(&scores[row], s);
      }
    }
  }
}

// ---- fallback kernels (used only if ws too small) ----
__global__ void k_transpose_w1(const float* __restrict__ W1, unsigned short* __restrict__ W1T) {
  __shared__ float tile[32][33];
  int bx = blockIdx.x, by = blockIdx.y;
  int tx = threadIdx.x, ty = threadIdx.y;
#pragma unroll
  for (int i = 0; i < 4; ++i)
    tile[ty + i * 8][tx] = W1[(by * 32 + ty + i * 8) * UNITS + bx * 32 + tx];
  __syncthreads();
#pragma unroll
  for (int i = 0; i < 4; ++i)
    W1T[(bx * 32 + ty + i * 8) * H + by * 32 + tx] = f2bf(tile[tx][ty + i * 8]);
}

__global__ void k_projq(const float* __restrict__ query, const float* __restrict__ W2,
                        const float* __restrict__ b2, float* __restrict__ projq) {
  __shared__ float q[H];
  int b = blockIdx.x;
  int u = blockIdx.y * 256 + threadIdx.x;
  for (int i = threadIdx.x; i < H; i += 256) q[i] = query[b * H + i];
  __syncthreads();
  float acc = 0.f;
#pragma unroll 8
  for (int k = 0; k < H; ++k) acc = fmaf(q[k], W2[k * UNITS + u], acc);
  projq[b * UNITS + u] = acc + b2[u];
}

#define FBM 128
#define FBN 128
#define FBK 64
#define LDK 72
__global__ __launch_bounds__(256) void k_score_f32(
    const float* __restrict__ values, const unsigned short* __restrict__ W1T,
    const float* __restrict__ b1, const float* __restrict__ projq,
    const float* __restrict__ V, float* __restrict__ scores)
{
  __shared__ unsigned short Asf[FBM][LDK];
  __shared__ unsigned short Bsf[FBN][LDK];
  const int tid = threadIdx.x;
  const int lane = tid & 63;
  const int wave = tid >> 6;
  const int wm = wave >> 1, wn = wave & 1;
  const int li = lane & 15, hi = lane >> 4;
  const int n0 = blockIdx.x * FBN;
  const int m0 = blockIdx.y * FBM;
  f32x4 acc[4][4] = {};
  for (int k0 = 0; k0 < H; k0 += FBK) {
    __syncthreads();
#pragma unroll
    for (int q = 0; q < 8; ++q) {
      int idx = q * 256 + tid;
      int row = idx >> 4;
      int kc = (idx & 15) << 2;
      float4 v = *reinterpret_cast<const float4*>(&values[(size_t)(m0 + row) * H + k0 + kc]);
      union { unsigned short h[4]; unsigned long long u64; } p;
      p.h[0] = f2bf(v.x); p.h[1] = f2bf(v.y); p.h[2] = f2bf(v.z); p.h[3] = f2bf(v.w);
      *reinterpret_cast<unsigned long long*>(&Asf[row][kc]) = p.u64;
    }
#pragma unroll
    for (int q = 0; q < 4; ++q) {
      int idx = q * 256 + tid;
      int row = idx >> 3;
      int kc = (idx & 7) << 3;
      *reinterpret_cast<u16x8*>(&Bsf[row][kc]) =
          *reinterpret_cast<const u16x8*>(&W1T[(size_t)(n0 + row) * H + k0 + kc]);
    }
    __syncthreads();
#pragma unroll
    for (int ks = 0; ks < 2; ++ks) {
      const int kofs = ks * 32 + 8 * hi;
      bf16x8 a[4], bb[4];
#pragma unroll
      for (int i = 0; i < 4; ++i)
        a[i] = *reinterpret_cast<const bf16x8*>(&Asf[wm * 64 + i * 16 + li][kofs]);
#pragma unroll
      for (int i = 0; i < 4; ++i)
        bb[i] = *reinterpret_cast<const bf16x8*>(&Bsf[wn * 64 + i * 16 + li][kofs]);
#pragma unroll
      for (int mi = 0; mi < 4; ++mi)
#pragma unroll
        for (int ni = 0; ni < 4; ++ni)
          acc[mi][ni] = __builtin_amdgcn_mfma_f32_16x16x32_bf16(a[mi], bb[ni], acc[mi][ni], 0, 0, 0);
    }
  }
  const int b = m0 >> 11;
  float bias[4], vv[4];
#pragma unroll
  for (int ni = 0; ni < 4; ++ni) {
    int u = n0 + wn * 64 + ni * 16 + li;
    bias[ni] = b1[u] + projq[b * UNITS + u];
    vv[ni] = V[u];
  }
#pragma unroll
  for (int mi = 0; mi < 4; ++mi) {
#pragma unroll
    for (int r = 0; r < 4; ++r) {
      float s = 0.f;
#pragma unroll
      for (int ni = 0; ni < 4; ++ni) {
        float x = acc[mi][ni][r] + bias[ni];
        float e = __expf(2.f * x);
        s += (1.f - 2.f / (e + 1.f)) * vv[ni];
      }
      s += __shfl_xor(s, 1);
      s += __shfl_xor(s, 2);
      s += __shfl_xor(s, 4);
      s += __shfl_xor(s, 8);
      if (li == 0) atomicAdd(&scores[m0 + wm * 64 + mi * 16 + hi * 4 + r], s);
    }
  }
}

// ---- softmax over S per batch; bv cancels ----
__global__ void k_softmax(const float* __restrict__ scores, float* __restrict__ wts) {
  __shared__ float red[8];
  int b = blockIdx.x;
  int t = threadIdx.x;
  float v[8];
  float mx = -3.4e38f;
#pragma unroll
  for (int i = 0; i < 8; ++i) {
    v[i] = scores[b * SEQ + i * 256 + t];
    mx = fmaxf(mx, v[i]);
  }
#pragma unroll
  for (int o = 1; o < 64; o <<= 1) mx = fmaxf(mx, __shfl_xor(mx, o));
  if ((t & 63) == 0) red[t >> 6] = mx;
  __syncthreads();
  mx = fmaxf(fmaxf(red[0], red[1]), fmaxf(red[2], red[3]));
  float sum = 0.f;
#pragma unroll
  for (int i = 0; i < 8; ++i) { v[i] = __expf(v[i] - mx); sum += v[i]; }
#pragma unroll
  for (int o = 1; o < 64; o <<= 1) sum += __shfl_xor(sum, o);
  if ((t & 63) == 0) red[4 + (t >> 6)] = sum;
  __syncthreads();
  float inv = 1.f / (red[4] + red[5] + red[6] + red[7]);
#pragma unroll
  for (int i = 0; i < 8; ++i) wts[b * SEQ + i * 256 + t] = v[i] * inv;
}

// ---- context from bf16 values: ctx[b][h] = sum_s w[b][s]*v[b][s][h] ----
__global__ void k_context_bf(const unsigned short* __restrict__ Vb,
                             const float* __restrict__ wts, float* __restrict__ ctx) {
  int b = blockIdx.x, sc = blockIdx.y;
  int h4 = threadIdx.x * 4;
  const unsigned short* vb = Vb + (size_t)b * SEQ * H;
  float a0 = 0, a1 = 0, a2 = 0, a3 = 0;
  int s0 = sc * 128;
#pragma unroll 4
  for (int s = s0; s < s0 + 128; ++s) {
    float w = wts[b * SEQ + s];
    ushort4 v = *reinterpret_cast<const ushort4*>(&vb[(size_t)s * H + h4]);
    a0 = fmaf(w, bf2f(v.x), a0);
    a1 = fmaf(w, bf2f(v.y), a1);
    a2 = fmaf(w, bf2f(v.z), a2);
    a3 = fmaf(w, bf2f(v.w), a3);
  }
  atomicAdd(&ctx[b * H + h4 + 0], a0);
  atomicAdd(&ctx[b * H + h4 + 1], a1);
  atomicAdd(&ctx[b * H + h4 + 2], a2);
  atomicAdd(&ctx[b * H + h4 + 3], a3);
}

// ---- fp32 context (fallback path) ----
__global__ void k_context(const float* __restrict__ values, const float* __restrict__ wts,
                          float* __restrict__ ctx) {
  int b = blockIdx.x, hc = blockIdx.y, sc = blockIdx.z;
  int h = hc * 256 + threadIdx.x;
  const float* vb = values + (size_t)b * SEQ * H;
  float acc = 0.f;
  int s0 = sc * 128;
#pragma unroll 4
  for (int s = s0; s < s0 + 128; ++s)
    acc = fmaf(wts[b * SEQ + s], vb[(size_t)s * H + h], acc);
  atomicAdd(&ctx[b * H + h], acc);
}

extern "C" void kernel_launch(void* const* d_in, const int* in_sizes, int n_in,
                              void* d_out, int out_size, void* d_ws, size_t ws_size,
                              hipStream_t stream) {
  (void)in_sizes; (void)n_in; (void)out_size;
  const float* query  = (const float*)d_in[0];
  const float* values = (const float*)d_in[1];
  const float* W1     = (const float*)d_in[2];
  const float* b1     = (const float*)d_in[3];
  const float* W2     = (const float*)d_in[4];
  const float* b2     = (const float*)d_in[5];
  const float* V      = (const float*)d_in[6];
  // d_in[7] = bv: cancels in softmax -> unused.

  float* out = (float*)d_out;
  float* ctx = out;             // [32][1024]
  float* wts = out + BATCH * H; // [32][2048]

  const size_t vb_bytes = (size_t)M_TOT * H * 2;  // 128 MB
  const size_t need = vb_bytes + (2u << 20) + (256u << 10) + (128u << 10);

  if (ws_size >= need) {
    char* ws = (char*)d_ws;
    unsigned short* Vb  = (unsigned short*)ws;
    unsigned short* W1T = (unsigned short*)(ws + vb_bytes);
    float* scores = (float*)(ws + vb_bytes + (2u << 20));
    float* projq  = (float*)(ws + vb_bytes + (2u << 20) + (256u << 10));

    hipMemsetAsync(scores, 0, M_TOT * sizeof(float), stream);
    hipMemsetAsync(ctx, 0, BATCH * H * sizeof(float), stream);

    k_prep<<<3200, 256, 0, stream>>>(values, Vb, W1, W1T, query, W2, b2, projq);
    k_score3<<<(M_TOT / BM) * (UNITS / BN), 512, 0, stream>>>(Vb, W1T, b1, projq, V, scores);
    k_softmax<<<BATCH, 256, 0, stream>>>(scores, wts);
    k_context_bf<<<dim3(BATCH, 16), 256, 0, stream>>>(Vb, wts, ctx);
  } else {
    char* ws = (char*)d_ws;
    unsigned short* W1T = (unsigned short*)ws;
    float* scores = (float*)(ws + (2u << 20));
    float* projq  = (float*)(ws + (2u << 20) + (256u << 10));

    hipMemsetAsync(scores, 0, M_TOT * sizeof(float), stream);
    hipMemsetAsync(ctx, 0, BATCH * H * sizeof(float), stream);

    k_transpose_w1<<<dim3(32, 32), dim3(32, 8), 0, stream>>>(W1, W1T);
    k_projq<<<dim3(32, 4), 256, 0, stream>>>(query, W2, b2, projq);
    k_score_f32<<<dim3(UNITS / FBN, M_TOT / FBM), 256, 0, stream>>>(values, W1T, b1, projq, V, scores);
    k_softmax<<<BATCH, 256, 0, stream>>>(scores, wts);
    k_context<<<dim3(BATCH, H / 256, 16), 256, 0, stream>>>(values, wts, ctx);
  }
}

// Round 15
// 319.714 us; speedup vs baseline: 1.0908x; 1.0311x over previous
//
#include <hip/hip_runtime.h>

#define H 1024
#define UNITS 1024
#define BATCH 32
#define SEQ 2048
#define M_TOT (BATCH * SEQ)  // 65536

typedef __attribute__((ext_vector_type(8))) short bf16x8;
typedef __attribute__((ext_vector_type(8))) unsigned short u16x8;
typedef __attribute__((ext_vector_type(4))) float f32x4;

__device__ __forceinline__ unsigned short f2bf(float f) {
  union { float f; unsigned u; } x; x.f = f;
  unsigned r = x.u + 0x7FFFu + ((x.u >> 16) & 1u);  // RTN-even
  return (unsigned short)(r >> 16);
}
__device__ __forceinline__ float bf2f(unsigned short h) {
  union { unsigned u; float f; } x; x.u = (unsigned)h << 16;
  return x.f;
}

// async global->LDS, 16B per lane; LDS dest = wave-uniform base + lane*16
__device__ __forceinline__ void gll16(const unsigned short* g, unsigned short* l) {
  __builtin_amdgcn_global_load_lds(
      (const __attribute__((address_space(1))) void*)g,
      (__attribute__((address_space(3))) void*)l, 16, 0, 0);
}

// ---- fused prep (R13, measured -10us): values cast (blocks 0..2047) +
//      W1 transpose (2048..3071) + projq (3072..3199).
__global__ void k_prep(const float* __restrict__ values, unsigned short* __restrict__ Vb,
                       const float* __restrict__ W1, unsigned short* __restrict__ W1T,
                       const float* __restrict__ query, const float* __restrict__ W2,
                       const float* __restrict__ b2, float* __restrict__ projq) {
  __shared__ float sh[1056];  // aliased: tile[32][33] (4224B) / q[1024] (4096B)
  const int blk = blockIdx.x;
  const int tid = threadIdx.x;
  if (blk < 2048) {
    for (int u = blk; u < 32768; u += 2048) {
      size_t i = ((size_t)u * 256 + tid) * 8;
      float4 v0 = *reinterpret_cast<const float4*>(values + i);
      float4 v1 = *reinterpret_cast<const float4*>(values + i + 4);
      union { unsigned short h[8]; u16x8 v; } p;
      p.h[0] = f2bf(v0.x); p.h[1] = f2bf(v0.y); p.h[2] = f2bf(v0.z); p.h[3] = f2bf(v0.w);
      p.h[4] = f2bf(v1.x); p.h[5] = f2bf(v1.y); p.h[6] = f2bf(v1.z); p.h[7] = f2bf(v1.w);
      *reinterpret_cast<u16x8*>(Vb + i) = p.v;
    }
  } else if (blk < 3072) {
    float (*tile)[33] = reinterpret_cast<float(*)[33]>(sh);
    const int t = blk - 2048;
    const int bx = t & 31, by = t >> 5;
    const int tx = tid & 31, ty = tid >> 5;  // 32 x 8
#pragma unroll
    for (int i = 0; i < 4; ++i)
      tile[ty + i * 8][tx] = W1[(by * 32 + ty + i * 8) * UNITS + bx * 32 + tx];
    __syncthreads();
#pragma unroll
    for (int i = 0; i < 4; ++i)
      W1T[(bx * 32 + ty + i * 8) * H + by * 32 + tx] = f2bf(tile[tx][ty + i * 8]);
  } else {
    float* q = sh;
    const int t = blk - 3072;       // 0..127
    const int b = t >> 2;
    const int u = (t & 3) * 256 + tid;
    for (int i = tid; i < H; i += 256) q[i] = query[b * H + i];
    __syncthreads();
    float acc = 0.f;
#pragma unroll 8
    for (int k = 0; k < H; ++k) acc = fmaf(q[k], W2[k * UNITS + u], acc);
    projq[b * UNITS + u] = acc + b2[u];
  }
}

// ============ 256x256 fused GEMM + tanh + dot(V) -> scores ===================
// CONSOLIDATION: R8's exact kernel — the measured best (183 us = 751 TF).
// Ring-4 BK=32, depth-3 prefetch, counted vmcnt(8) at tile top (waits ONLY
// tile c's 4 loads, issued 3 tiles earlier; c+1,c+2 stay in flight across
// the barrier — never drained to 0). R7-proven conflict-free packed layout
// (2 logical rows per 128-B LDS row; 0 conflicts measured R7/R8/R13).
// Single read-burst + 32-MFMA cluster; compiler inserts the lgkm waits.
// Schedule variants R9-R13 (phase-split, reg-pipeline, counted lgkm,
// 2-block TLP) all measured neutral-to-worse; this is the family optimum.
#define BM 256
#define BN 256
#define NKT 32  // K-tiles of 32

__global__ __launch_bounds__(512, 2) void k_score3(
    const unsigned short* __restrict__ Vb,   // values bf16 [M_TOT][H]
    const unsigned short* __restrict__ W1T,  // [UNITS][H] bf16
    const float* __restrict__ b1,
    const float* __restrict__ projq,         // [BATCH][UNITS]
    const float* __restrict__ V,
    float* __restrict__ scores)              // [M_TOT], pre-zeroed
{
  __shared__ unsigned short As[4][128][64];  // 64 KB (ring of 4 K-tiles)
  __shared__ unsigned short Bs[4][128][64];  // 64 KB

  const int tid = threadIdx.x;
  const int lane = tid & 63;
  const int wave = tid >> 6;        // 0..7
  const int wm = wave >> 2;         // 0..1 -> rows wm*128..+128
  const int wn = wave & 3;          // 0..3 -> cols wn*64..+64
  const int li = lane & 15, hi = lane >> 4;
  const int lr2 = li >> 1;
  const int pcol = (((((li & 1) << 2) + hi) ^ lr2) & 7) << 3;  // read slot (halves)

  // XCD-bijective swizzle: all 4 N-tiles of an M-tile on one XCD, consecutive.
  const int g = blockIdx.x;
  const int xcd = g & 7;
  const int local = g >> 3;          // 0..127
  const int n_t = local & 3;
  const int m_t = xcd + ((local >> 2) << 3);  // 0..255, bijective
  const int m0 = m_t * BM;
  const int n0 = n_t * BN;

  // staging: chunk = 16 global rows x 32 halves = 1 KB = one gll16.
  // lane l: s=(l&7)^(l>>3); grow = 2*(l>>3)+(s>>2); gcol halves = (s&3)*8
  const int sL = (lane & 7) ^ (lane >> 3);
  const int srow = 2 * (lane >> 3) + (sL >> 2);
  const int scol = (sL & 3) << 3;

  auto STAGE_A = [&](int bf, int kt) {
#pragma unroll
    for (int q = 0; q < 2; ++q) {
      int mb = wave * 32 + q * 16;
      gll16(&Vb[(size_t)(m0 + mb + srow) * H + kt * 32 + scol],
            &As[bf][wave * 16 + q * 8][0]);
    }
  };
  auto STAGE_B = [&](int bf, int kt) {
#pragma unroll
    for (int q = 0; q < 2; ++q) {
      int mb = wave * 32 + q * 16;
      gll16(&W1T[(size_t)(n0 + mb + srow) * H + kt * 32 + scol],
            &Bs[bf][wave * 16 + q * 8][0]);
    }
  };

  f32x4 acc[8][4] = {};

  // prologue: stage tiles 0,1,2 (12 loads/wave; issue order = ledger order)
  STAGE_A(0, 0); STAGE_B(0, 0);
  STAGE_A(1, 1); STAGE_B(1, 1);
  STAGE_A(2, 2); STAGE_B(2, 2);

#pragma unroll 4
  for (int c = 0; c < NKT; ++c) {
    const int buf = c & 3;
    const int nbuf = (c + 3) & 3;
    const int cn = (c < NKT - 3) ? c + 3 : NKT - 1;  // tail: dup-stage tile 31

    // tile c's 4 loads landed (issued 3 tiles ago); c+1,c+2 stay in flight
    asm volatile("s_waitcnt vmcnt(8)" ::: "memory");
    __builtin_amdgcn_s_barrier();

    bf16x8 a[8], b[4];
#pragma unroll
    for (int i = 0; i < 8; ++i)
      a[i] = *reinterpret_cast<const bf16x8*>(&As[buf][wm * 64 + i * 8 + lr2][pcol]);
    STAGE_A(nbuf, cn);
#pragma unroll
    for (int j = 0; j < 4; ++j)
      b[j] = *reinterpret_cast<const bf16x8*>(&Bs[buf][wn * 32 + j * 8 + lr2][pcol]);
    STAGE_B(nbuf, cn);

    __builtin_amdgcn_s_setprio(1);
#pragma unroll
    for (int i = 0; i < 8; ++i)
#pragma unroll
      for (int j = 0; j < 4; ++j)
        acc[i][j] = __builtin_amdgcn_mfma_f32_16x16x32_bf16(a[i], b[j], acc[i][j], 0, 0, 0);
    __builtin_amdgcn_s_setprio(0);
  }

  // epilogue: partial score[row] = sum_u tanh(acc + b1[u] + projq[b][u]) * V[u]
  const int b = m0 >> 11;  // BM=256 divides SEQ=2048 -> batch uniform per block
  float bias[4], vv[4];
#pragma unroll
  for (int j = 0; j < 4; ++j) {
    int u = n0 + wn * 64 + j * 16 + li;
    bias[j] = b1[u] + projq[b * UNITS + u];
    vv[j] = V[u];
  }
#pragma unroll
  for (int mi = 0; mi < 8; ++mi) {
#pragma unroll
    for (int r = 0; r < 4; ++r) {
      float s = 0.f;
#pragma unroll
      for (int j = 0; j < 4; ++j) {
        float x = acc[mi][j][r] + bias[j];
        float e = __expf(2.f * x);       // tanh(x) = 1 - 2/(e^(2x)+1)
        s += (1.f - 2.f / (e + 1.f)) * vv[j];
      }
      s += __shfl_xor(s, 1);
      s += __shfl_xor(s, 2);
      s += __shfl_xor(s, 4);
      s += __shfl_xor(s, 8);
      if (li == 0) {
        int row = m0 + wm * 128 + mi * 16 + hi * 4 + r;
        atomicAdd(&scores[row], s);
      }
    }
  }
}

// ---- fallback kernels (used only if ws too small) ----
__global__ void k_transpose_w1(const float* __restrict__ W1, unsigned short* __restrict__ W1T) {
  __shared__ float tile[32][33];
  int bx = blockIdx.x, by = blockIdx.y;
  int tx = threadIdx.x, ty = threadIdx.y;
#pragma unroll
  for (int i = 0; i < 4; ++i)
    tile[ty + i * 8][tx] = W1[(by * 32 + ty + i * 8) * UNITS + bx * 32 + tx];
  __syncthreads();
#pragma unroll
  for (int i = 0; i < 4; ++i)
    W1T[(bx * 32 + ty + i * 8) * H + by * 32 + tx] = f2bf(tile[tx][ty + i * 8]);
}

__global__ void k_projq(const float* __restrict__ query, const float* __restrict__ W2,
                        const float* __restrict__ b2, float* __restrict__ projq) {
  __shared__ float q[H];
  int b = blockIdx.x;
  int u = blockIdx.y * 256 + threadIdx.x;
  for (int i = threadIdx.x; i < H; i += 256) q[i] = query[b * H + i];
  __syncthreads();
  float acc = 0.f;
#pragma unroll 8
  for (int k = 0; k < H; ++k) acc = fmaf(q[k], W2[k * UNITS + u], acc);
  projq[b * UNITS + u] = acc + b2[u];
}

#define FBM 128
#define FBN 128
#define FBK 64
#define LDK 72
__global__ __launch_bounds__(256) void k_score_f32(
    const float* __restrict__ values, const unsigned short* __restrict__ W1T,
    const float* __restrict__ b1, const float* __restrict__ projq,
    const float* __restrict__ V, float* __restrict__ scores)
{
  __shared__ unsigned short Asf[FBM][LDK];
  __shared__ unsigned short Bsf[FBN][LDK];
  const int tid = threadIdx.x;
  const int lane = tid & 63;
  const int wave = tid >> 6;
  const int wm = wave >> 1, wn = wave & 1;
  const int li = lane & 15, hi = lane >> 4;
  const int n0 = blockIdx.x * FBN;
  const int m0 = blockIdx.y * FBM;
  f32x4 acc[4][4] = {};
  for (int k0 = 0; k0 < H; k0 += FBK) {
    __syncthreads();
#pragma unroll
    for (int q = 0; q < 8; ++q) {
      int idx = q * 256 + tid;
      int row = idx >> 4;
      int kc = (idx & 15) << 2;
      float4 v = *reinterpret_cast<const float4*>(&values[(size_t)(m0 + row) * H + k0 + kc]);
      union { unsigned short h[4]; unsigned long long u64; } p;
      p.h[0] = f2bf(v.x); p.h[1] = f2bf(v.y); p.h[2] = f2bf(v.z); p.h[3] = f2bf(v.w);
      *reinterpret_cast<unsigned long long*>(&Asf[row][kc]) = p.u64;
    }
#pragma unroll
    for (int q = 0; q < 4; ++q) {
      int idx = q * 256 + tid;
      int row = idx >> 3;
      int kc = (idx & 7) << 3;
      *reinterpret_cast<u16x8*>(&Bsf[row][kc]) =
          *reinterpret_cast<const u16x8*>(&W1T[(size_t)(n0 + row) * H + k0 + kc]);
    }
    __syncthreads();
#pragma unroll
    for (int ks = 0; ks < 2; ++ks) {
      const int kofs = ks * 32 + 8 * hi;
      bf16x8 a[4], bb[4];
#pragma unroll
      for (int i = 0; i < 4; ++i)
        a[i] = *reinterpret_cast<const bf16x8*>(&Asf[wm * 64 + i * 16 + li][kofs]);
#pragma unroll
      for (int i = 0; i < 4; ++i)
        bb[i] = *reinterpret_cast<const bf16x8*>(&Bsf[wn * 64 + i * 16 + li][kofs]);
#pragma unroll
      for (int mi = 0; mi < 4; ++mi)
#pragma unroll
        for (int ni = 0; ni < 4; ++ni)
          acc[mi][ni] = __builtin_amdgcn_mfma_f32_16x16x32_bf16(a[mi], bb[ni], acc[mi][ni], 0, 0, 0);
    }
  }
  const int b = m0 >> 11;
  float bias[4], vv[4];
#pragma unroll
  for (int ni = 0; ni < 4; ++ni) {
    int u = n0 + wn * 64 + ni * 16 + li;
    bias[ni] = b1[u] + projq[b * UNITS + u];
    vv[ni] = V[u];
  }
#pragma unroll
  for (int mi = 0; mi < 4; ++mi) {
#pragma unroll
    for (int r = 0; r < 4; ++r) {
      float s = 0.f;
#pragma unroll
      for (int ni = 0; ni < 4; ++ni) {
        float x = acc[mi][ni][r] + bias[ni];
        float e = __expf(2.f * x);
        s += (1.f - 2.f / (e + 1.f)) * vv[ni];
      }
      s += __shfl_xor(s, 1);
      s += __shfl_xor(s, 2);
      s += __shfl_xor(s, 4);
      s += __shfl_xor(s, 8);
      if (li == 0) atomicAdd(&scores[m0 + wm * 64 + mi * 16 + hi * 4 + r], s);
    }
  }
}

// ---- softmax over S per batch; bv cancels ----
__global__ void k_softmax(const float* __restrict__ scores, float* __restrict__ wts) {
  __shared__ float red[8];
  int b = blockIdx.x;
  int t = threadIdx.x;
  float v[8];
  float mx = -3.4e38f;
#pragma unroll
  for (int i = 0; i < 8; ++i) {
    v[i] = scores[b * SEQ + i * 256 + t];
    mx = fmaxf(mx, v[i]);
  }
#pragma unroll
  for (int o = 1; o < 64; o <<= 1) mx = fmaxf(mx, __shfl_xor(mx, o));
  if ((t & 63) == 0) red[t >> 6] = mx;
  __syncthreads();
  mx = fmaxf(fmaxf(red[0], red[1]), fmaxf(red[2], red[3]));
  float sum = 0.f;
#pragma unroll
  for (int i = 0; i < 8; ++i) { v[i] = __expf(v[i] - mx); sum += v[i]; }
#pragma unroll
  for (int o = 1; o < 64; o <<= 1) sum += __shfl_xor(sum, o);
  if ((t & 63) == 0) red[4 + (t >> 6)] = sum;
  __syncthreads();
  float inv = 1.f / (red[4] + red[5] + red[6] + red[7]);
#pragma unroll
  for (int i = 0; i < 8; ++i) wts[b * SEQ + i * 256 + t] = v[i] * inv;
}

// ---- context from bf16 values: ctx[b][h] = sum_s w[b][s]*v[b][s][h] ----
__global__ void k_context_bf(const unsigned short* __restrict__ Vb,
                             const float* __restrict__ wts, float* __restrict__ ctx) {
  int b = blockIdx.x, sc = blockIdx.y;
  int h4 = threadIdx.x * 4;
  const unsigned short* vb = Vb + (size_t)b * SEQ * H;
  float a0 = 0, a1 = 0, a2 = 0, a3 = 0;
  int s0 = sc * 128;
#pragma unroll 4
  for (int s = s0; s < s0 + 128; ++s) {
    float w = wts[b * SEQ + s];
    ushort4 v = *reinterpret_cast<const ushort4*>(&vb[(size_t)s * H + h4]);
    a0 = fmaf(w, bf2f(v.x), a0);
    a1 = fmaf(w, bf2f(v.y), a1);
    a2 = fmaf(w, bf2f(v.z), a2);
    a3 = fmaf(w, bf2f(v.w), a3);
  }
  atomicAdd(&ctx[b * H + h4 + 0], a0);
  atomicAdd(&ctx[b * H + h4 + 1], a1);
  atomicAdd(&ctx[b * H + h4 + 2], a2);
  atomicAdd(&ctx[b * H + h4 + 3], a3);
}

// ---- fp32 context (fallback path) ----
__global__ void k_context(const float* __restrict__ values, const float* __restrict__ wts,
                          float* __restrict__ ctx) {
  int b = blockIdx.x, hc = blockIdx.y, sc = blockIdx.z;
  int h = hc * 256 + threadIdx.x;
  const float* vb = values + (size_t)b * SEQ * H;
  float acc = 0.f;
  int s0 = sc * 128;
#pragma unroll 4
  for (int s = s0; s < s0 + 128; ++s)
    acc = fmaf(wts[b * SEQ + s], vb[(size_t)s * H + h], acc);
  atomicAdd(&ctx[b * H + h], acc);
}

extern "C" void kernel_launch(void* const* d_in, const int* in_sizes, int n_in,
                              void* d_out, int out_size, void* d_ws, size_t ws_size,
                              hipStream_t stream) {
  (void)in_sizes; (void)n_in; (void)out_size;
  const float* query  = (const float*)d_in[0];
  const float* values = (const float*)d_in[1];
  const float* W1     = (const float*)d_in[2];
  const float* b1     = (const float*)d_in[3];
  const float* W2     = (const float*)d_in[4];
  const float* b2     = (const float*)d_in[5];
  const float* V      = (const float*)d_in[6];
  // d_in[7] = bv: cancels in softmax -> unused.

  float* out = (float*)d_out;
  float* ctx = out;             // [32][1024]
  float* wts = out + BATCH * H; // [32][2048]

  const size_t vb_bytes = (size_t)M_TOT * H * 2;  // 128 MB
  const size_t need = vb_bytes + (2u << 20) + (256u << 10) + (128u << 10);

  if (ws_size >= need) {
    char* ws = (char*)d_ws;
    unsigned short* Vb  = (unsigned short*)ws;
    unsigned short* W1T = (unsigned short*)(ws + vb_bytes);
    float* scores = (float*)(ws + vb_bytes + (2u << 20));
    float* projq  = (float*)(ws + vb_bytes + (2u << 20) + (256u << 10));

    hipMemsetAsync(scores, 0, M_TOT * sizeof(float), stream);
    hipMemsetAsync(ctx, 0, BATCH * H * sizeof(float), stream);

    k_prep<<<3200, 256, 0, stream>>>(values, Vb, W1, W1T, query, W2, b2, projq);
    k_score3<<<(M_TOT / BM) * (UNITS / BN), 512, 0, stream>>>(Vb, W1T, b1, projq, V, scores);
    k_softmax<<<BATCH, 256, 0, stream>>>(scores, wts);
    k_context_bf<<<dim3(BATCH, 16), 256, 0, stream>>>(Vb, wts, ctx);
  } else {
    char* ws = (char*)d_ws;
    unsigned short* W1T = (unsigned short*)ws;
    float* scores = (float*)(ws + (2u << 20));
    float* projq  = (float*)(ws + (2u << 20) + (256u << 10));

    hipMemsetAsync(scores, 0, M_TOT * sizeof(float), stream);
    hipMemsetAsync(ctx, 0, BATCH * H * sizeof(float), stream);

    k_transpose_w1<<<dim3(32, 32), dim3(32, 8), 0, stream>>>(W1, W1T);
    k_projq<<<dim3(32, 4), 256, 0, stream>>>(query, W2, b2, projq);
    k_score_f32<<<dim3(UNITS / FBN, M_TOT / FBM), 256, 0, stream>>>(values, W1T, b1, projq, V, scores);
    k_softmax<<<BATCH, 256, 0, stream>>>(scores, wts);
    k_context<<<dim3(BATCH, H / 256, 16), 256, 0, stream>>>(values, wts, ctx);
  }
}